// Round 1
// baseline (1196.835 us; speedup 1.0000x reference)
//
#include <hip/hip_runtime.h>

#define T_LEN 4096
#define H_DIM 512
#define N_TAGS 50257

typedef _Float16 f16;
typedef __attribute__((ext_vector_type(8))) _Float16 f16x8;
typedef __attribute__((ext_vector_type(4))) _Float16 f16x4;
typedef __attribute__((ext_vector_type(4))) float f32x4;

// ---------------- ws layout ----------------
#define XG_OFF    0ull                  // 4096*512 f16        = 4,194,304
#define WIH_OFF   4194304ull            // 512*512 f16         =   524,288
#define WRNN_OFF  4718592ull            // 65536 dwords        =   262,144
#define XP_OFF    5242880ull            // 4096*512 f32        = 8,388,608
#define HS_OFF    13631488ull           // 4096*512 f16        = 4,194,304
#define WOUT_OFF  17825792ull           // 50257*512 f16       = 51,463,168
#define PART_OFF  69288960ull           // 393*4096 float2     = 12,877,824
#define LSE_OFF   82166784ull           // 4096 f32
#define WS_NEEDED 82183168ull

#define WMAX 0.04419417382f             // 1/sqrt(512)
#define NBLK 393                        // ceil(50257/128)

__device__ __forceinline__ void gload_lds16(const void* g, void* l) {
    __builtin_amdgcn_global_load_lds(
        (const __attribute__((address_space(1))) unsigned*)g,
        (__attribute__((address_space(3))) unsigned*)l, 16, 0, 0);
}

__device__ __forceinline__ float tanh_fast(float x) {
    float e = __expf(2.f * x);
    return 1.f - 2.f / (e + 1.f);
}

// ---------------- prep kernels ----------------
__global__ void k_gather_cast(const int* __restrict__ sent, const float* __restrict__ emb,
                              f16* __restrict__ xg) {
    int idx = blockIdx.x * 256 + threadIdx.x;      // 4096*512 exact
    int t = idx >> 9, e = idx & 511;
    xg[idx] = (f16)emb[(size_t)sent[t] * 512 + e];
}

__global__ void k_cast_f16(const float* __restrict__ src, f16* __restrict__ dst, unsigned n) {
    for (unsigned i = blockIdx.x * blockDim.x + threadIdx.x; i < n; i += gridDim.x * blockDim.x)
        dst[i] = (f16)src[i];
}

__global__ void k_prep_wrnn(const float* __restrict__ whh, int* __restrict__ wrnn) {
    int D = blockIdx.x * 256 + threadIdx.x;        // 65536 dwords exact
    int l = D & 63, c = (D >> 6) & 63, w = D >> 12;
    int k = c >> 4, q = c & 15, g = w & 7, hh = w >> 3;
    int o = hh * 256 + l * 4 + k;
    int res = 0;
    for (int b = 0; b < 4; ++b) {
        int j = g * 64 + q * 4 + b;
        float v = whh[o * 512 + j] * (127.0f / WMAX);
        int qv = __float2int_rn(v);
        qv = qv < -127 ? -127 : (qv > 127 ? 127 : qv);
        res |= (qv & 0xff) << (8 * b);
    }
    wrnn[D] = res;
}

// ---------------- K1: xp = x @ W_ih^T + b_ih + b_hh ----------------
__launch_bounds__(256)
__global__ void k_gemm_xp(const f16* __restrict__ A, const f16* __restrict__ B,
                          const float* __restrict__ bih, const float* __restrict__ bhh,
                          float* __restrict__ xp) {
    __shared__ f16 As[128 * 64];
    __shared__ f16 Bs[128 * 64];
    int nb = blockIdx.x, mb = blockIdx.y;
    int tid = threadIdx.x;
    int lane = tid & 63, wv = tid >> 6;
    int wm = wv >> 1, wn = wv & 1;
    f32x4 acc[4][4] = {};
    for (int kk = 0; kk < 8; ++kk) {
        __syncthreads();
        for (int p = 0; p < 4; ++p) {
            int f = p * 256 + tid;
            int row = f >> 3, c16 = f & 7;
            const f16* ga = A + ((size_t)(mb * 128 + row) * 512 + kk * 64 + c16 * 8);
            const f16* gb = B + ((size_t)(nb * 128 + row) * 512 + kk * 64 + c16 * 8);
            gload_lds16(ga, &As[(p * 256 + wv * 64) * 8]);
            gload_lds16(gb, &Bs[(p * 256 + wv * 64) * 8]);
        }
        __syncthreads();
        for (int k2 = 0; k2 < 2; ++k2) {
            int krow = k2 * 32 + (lane >> 4) * 8;
            f16x8 a[4], b[4];
            for (int mi = 0; mi < 4; ++mi)
                a[mi] = *(const f16x8*)&As[(wm * 64 + mi * 16 + (lane & 15)) * 64 + krow];
            for (int ni = 0; ni < 4; ++ni)
                b[ni] = *(const f16x8*)&Bs[(wn * 64 + ni * 16 + (lane & 15)) * 64 + krow];
            for (int mi = 0; mi < 4; ++mi)
                for (int ni = 0; ni < 4; ++ni)
                    acc[mi][ni] = __builtin_amdgcn_mfma_f32_16x16x32_f16(a[mi], b[ni], acc[mi][ni], 0, 0, 0);
        }
    }
    for (int mi = 0; mi < 4; ++mi)
        for (int ni = 0; ni < 4; ++ni)
            for (int r = 0; r < 4; ++r) {
                int row = mb * 128 + wm * 64 + mi * 16 + (lane >> 4) * 4 + r;
                int col = nb * 128 + wn * 64 + ni * 16 + (lane & 15);
                xp[(size_t)row * 512 + col] = acc[mi][ni][r] + bih[col] + bhh[col];
            }
}

// ---------------- K2: chunked RNN, int8 W in VGPRs ----------------
__launch_bounds__(1024)
__global__ void k_rnn(const int* __restrict__ wrnn, const float* __restrict__ xp,
                      f16* __restrict__ hs) {
    __shared__ __align__(16) int h8[128];
    __shared__ __align__(16) float part[8][512];
    const int tid = threadIdx.x;
    const int lane = tid & 63, wv = tid >> 6;
    const int g = wv & 7, hh = wv >> 3;
    const int chunk = blockIdx.x;                 // 0..255
    const int out_start = chunk * 16;
    const int t_start = out_start >= 128 ? out_start - 128 : 0;
    const int t_end = out_start + 16;

    int W[64];
#pragma unroll
    for (int cc = 0; cc < 64; ++cc) W[cc] = wrnn[(wv * 64 + cc) * 64 + lane];

    if (tid < 128) h8[tid] = 0;
    float4 xpv = {};
    if (tid < 128) xpv = *(const float4*)&xp[(size_t)t_start * 512 + tid * 4];
    __syncthreads();

    for (int t = t_start; t < t_end; ++t) {
        int hbuf[16];
#pragma unroll
        for (int q4 = 0; q4 < 4; ++q4)
            *(int4*)&hbuf[q4 * 4] = *(const int4*)&h8[g * 16 + q4 * 4];
        int a0 = 0, a1 = 0, a2 = 0, a3 = 0;
#pragma unroll
        for (int q = 0; q < 16; ++q) {
            int hq = hbuf[q];
            a0 = __builtin_amdgcn_sdot4(W[q], hq, a0, false);
            a1 = __builtin_amdgcn_sdot4(W[16 + q], hq, a1, false);
            a2 = __builtin_amdgcn_sdot4(W[32 + q], hq, a2, false);
            a3 = __builtin_amdgcn_sdot4(W[48 + q], hq, a3, false);
        }
        float4 pv;
        pv.x = (float)a0; pv.y = (float)a1; pv.z = (float)a2; pv.w = (float)a3;
        *(float4*)&part[g][hh * 256 + lane * 4] = pv;
        __syncthreads();
        if (tid < 128) {
            float sx = 0.f, sy = 0.f, sz = 0.f, sw = 0.f;
#pragma unroll
            for (int gg = 0; gg < 8; ++gg) {
                float4 p = *(const float4*)&part[gg][tid * 4];
                sx += p.x; sy += p.y; sz += p.z; sw += p.w;
            }
            const float DEQ = WMAX / (127.f * 127.f);
            float h0 = tanh_fast(sx * DEQ + xpv.x);
            float h1 = tanh_fast(sy * DEQ + xpv.y);
            float h2 = tanh_fast(sz * DEQ + xpv.z);
            float h3 = tanh_fast(sw * DEQ + xpv.w);
            if (t + 1 < t_end) xpv = *(const float4*)&xp[(size_t)(t + 1) * 512 + tid * 4];
            int q0 = __float2int_rn(h0 * 127.f), q1 = __float2int_rn(h1 * 127.f);
            int q2 = __float2int_rn(h2 * 127.f), q3 = __float2int_rn(h3 * 127.f);
            h8[tid] = (q0 & 255) | ((q1 & 255) << 8) | ((q2 & 255) << 16) | (q3 << 24);
            if (t >= out_start) {
                f16x4 hv;
                hv[0] = (f16)h0; hv[1] = (f16)h1; hv[2] = (f16)h2; hv[3] = (f16)h3;
                *(f16x4*)&hs[(size_t)t * 512 + tid * 4] = hv;
            }
        }
        __syncthreads();
    }
}

// ---------------- K3: logits GEMM + per-tile softmax partials ----------------
__launch_bounds__(256)
__global__ void k_gemm_out(const f16* __restrict__ A, const f16* __restrict__ B,
                           const float* __restrict__ bout, float* __restrict__ out,
                           float2* __restrict__ partials) {
    __shared__ f16 As[128 * 64];
    __shared__ f16 Bs[128 * 64];
    __shared__ float redm[2][128];
    __shared__ float reds[2][128];
    int nb = blockIdx.x, mb = blockIdx.y;
    int tid = threadIdx.x;
    int lane = tid & 63, wv = tid >> 6;
    int wm = wv >> 1, wn = wv & 1;
    f32x4 acc[4][4] = {};
    for (int kk = 0; kk < 8; ++kk) {
        __syncthreads();
        for (int p = 0; p < 4; ++p) {
            int f = p * 256 + tid;
            int row = f >> 3, c16 = f & 7;
            const f16* ga = A + ((size_t)(mb * 128 + row) * 512 + kk * 64 + c16 * 8);
            int rg = nb * 128 + row; if (rg > N_TAGS - 1) rg = N_TAGS - 1;
            const f16* gb = B + ((size_t)rg * 512 + kk * 64 + c16 * 8);
            gload_lds16(ga, &As[(p * 256 + wv * 64) * 8]);
            gload_lds16(gb, &Bs[(p * 256 + wv * 64) * 8]);
        }
        __syncthreads();
        for (int k2 = 0; k2 < 2; ++k2) {
            int krow = k2 * 32 + (lane >> 4) * 8;
            f16x8 a[4], b[4];
            for (int mi = 0; mi < 4; ++mi)
                a[mi] = *(const f16x8*)&As[(wm * 64 + mi * 16 + (lane & 15)) * 64 + krow];
            for (int ni = 0; ni < 4; ++ni)
                b[ni] = *(const f16x8*)&Bs[(wn * 64 + ni * 16 + (lane & 15)) * 64 + krow];
            for (int mi = 0; mi < 4; ++mi)
                for (int ni = 0; ni < 4; ++ni)
                    acc[mi][ni] = __builtin_amdgcn_mfma_f32_16x16x32_f16(a[mi], b[ni], acc[mi][ni], 0, 0, 0);
        }
    }
    int colb[4]; float bo[4]; bool valid[4];
    for (int ni = 0; ni < 4; ++ni) {
        colb[ni] = nb * 128 + wn * 64 + ni * 16 + (lane & 15);
        valid[ni] = colb[ni] < N_TAGS;
        bo[ni] = valid[ni] ? bout[colb[ni]] : 0.f;
    }
    for (int mi = 0; mi < 4; ++mi)
        for (int r = 0; r < 4; ++r) {
            int lr = wm * 64 + mi * 16 + (lane >> 4) * 4 + r;
            int row = mb * 128 + lr;
            float v[4]; float mx = -3.4e38f;
            for (int ni = 0; ni < 4; ++ni) {
                v[ni] = acc[mi][ni][r] + bo[ni];
                if (valid[ni]) mx = fmaxf(mx, v[ni]);
            }
            for (int off = 1; off < 16; off <<= 1) mx = fmaxf(mx, __shfl_xor(mx, off));
            float se = 0.f;
            for (int ni = 0; ni < 4; ++ni)
                if (valid[ni]) {
                    se += __expf(v[ni] - mx);
                    out[(size_t)row * N_TAGS + colb[ni]] = v[ni];
                }
            for (int off = 1; off < 16; off <<= 1) se += __shfl_xor(se, off);
            if ((lane & 15) == 0) { redm[wn][lr] = mx; reds[wn][lr] = se; }
        }
    __syncthreads();
    if (tid < 128) {
        float m0 = redm[0][tid], m1 = redm[1][tid];
        float s0 = reds[0][tid], s1 = reds[1][tid];
        float m = fmaxf(m0, m1);
        float s = s0 * __expf(m0 - m) + s1 * __expf(m1 - m);
        partials[(size_t)nb * 4096 + mb * 128 + tid] = make_float2(m, s);
    }
}

// ---------------- K4: lse per row ----------------
__global__ void k_lse(const float2* __restrict__ partials, float* __restrict__ lse) {
    int wv = threadIdx.x >> 6, lane = threadIdx.x & 63;
    int row = blockIdx.x * 4 + wv;
    float m = -3.4e38f, s = 0.f;
    for (int p = lane; p < NBLK; p += 64) {
        float2 pr = partials[(size_t)p * 4096 + row];
        float nm = fmaxf(m, pr.x);
        s = s * __expf(m - nm) + pr.y * __expf(pr.x - nm);
        m = nm;
    }
    for (int off = 1; off < 64; off <<= 1) {
        float om = __shfl_xor(m, off), os = __shfl_xor(s, off);
        float nm = fmaxf(m, om);
        s = s * __expf(m - nm) + os * __expf(om - nm);
        m = nm;
    }
    if (lane == 0) lse[row] = m + logf(s);
}

// ---------------- K5: out -= lse[row] ----------------
__global__ void k_sub(float* __restrict__ out, const float* __restrict__ lse, unsigned n) {
    unsigned stride = gridDim.x * blockDim.x;
    for (unsigned i = blockIdx.x * blockDim.x + threadIdx.x; i < n; i += stride) {
        unsigned row = i / (unsigned)N_TAGS;
        out[i] -= lse[row];
    }
}

extern "C" void kernel_launch(void* const* d_in, const int* in_sizes, int n_in,
                              void* d_out, int out_size, void* d_ws, size_t ws_size,
                              hipStream_t stream) {
    if (ws_size < WS_NEEDED) return;
    const int*   sent = (const int*)d_in[0];
    const float* emb  = (const float*)d_in[1];
    const float* wih  = (const float*)d_in[2];
    const float* whh  = (const float*)d_in[3];
    const float* bih  = (const float*)d_in[4];
    const float* bhh  = (const float*)d_in[5];
    const float* wout = (const float*)d_in[6];
    const float* bout = (const float*)d_in[7];
    char* ws = (char*)d_ws;
    f16*    xg    = (f16*)(ws + XG_OFF);
    f16*    wihf  = (f16*)(ws + WIH_OFF);
    int*    wrnn  = (int*)(ws + WRNN_OFF);
    float*  xp    = (float*)(ws + XP_OFF);
    f16*    hsb   = (f16*)(ws + HS_OFF);
    f16*    woutf = (f16*)(ws + WOUT_OFF);
    float2* part  = (float2*)(ws + PART_OFF);
    float*  lse   = (float*)(ws + LSE_OFF);

    k_gather_cast<<<8192, 256, 0, stream>>>(sent, emb, xg);
    k_cast_f16<<<1024, 256, 0, stream>>>(wih, wihf, 512u * 512u);
    k_cast_f16<<<4096, 256, 0, stream>>>(wout, woutf, (unsigned)N_TAGS * 512u);
    k_prep_wrnn<<<256, 256, 0, stream>>>(whh, wrnn);
    k_gemm_xp<<<dim3(4, 32), 256, 0, stream>>>(xg, wihf, bih, bhh, xp);
    k_rnn<<<256, 1024, 0, stream>>>(wrnn, xp, hsb);
    k_gemm_out<<<dim3(NBLK, 32), 256, 0, stream>>>(hsb, woutf, bout, (float*)d_out, part);
    k_lse<<<1024, 256, 0, stream>>>(part, lse);
    k_sub<<<8192, 256, 0, stream>>>((float*)d_out, lse, 4096u * (unsigned)N_TAGS);
}

// Round 2
// 1074.310 us; speedup vs baseline: 1.1141x; 1.1141x over previous
//
#include <hip/hip_runtime.h>

#define T_LEN 4096
#define H_DIM 512
#define N_TAGS 50257
#define LG_STRIDE 50304                 // N_TAGS padded to mult of 128 elems

typedef _Float16 f16;
typedef __attribute__((ext_vector_type(8))) _Float16 f16x8;
typedef __attribute__((ext_vector_type(4))) _Float16 f16x4;
typedef __attribute__((ext_vector_type(4))) float f32x4;

// ---------------- ws layout ----------------
#define XG_OFF    0ull                  // 4096*512 f16        = 4,194,304
#define WIH_OFF   4194304ull            // 512*512 f16         =   524,288
#define WRNN_OFF  4718592ull            // 65536 dwords        =   262,144
#define XP_OFF    5242880ull            // 4096*512 f32        = 8,388,608
#define HS_OFF    13631488ull           // 4096*512 f16        = 4,194,304
#define WOUT_OFF  17825792ull           // 50257*512 f16       = 51,463,168
#define PART_OFF  69288960ull           // 393*4096 float2     = 12,877,824
#define LSE_OFF   82166784ull           // 4096 f32            =    16,384
#define WS_NEEDED 82183168ull
#define LG_OFF    82183168ull           // 4096*50304 f16      = 412,090,368
#define WS_BIG    494273536ull

#define WMAX 0.04419417382f             // 1/sqrt(512)
#define NBLK 393                        // ceil(50257/128)

__device__ __forceinline__ void gload_lds16(const void* g, void* l) {
    __builtin_amdgcn_global_load_lds(
        (const __attribute__((address_space(1))) unsigned*)g,
        (__attribute__((address_space(3))) unsigned*)l, 16, 0, 0);
}

__device__ __forceinline__ float tanh_fast(float x) {
    float e = __expf(2.f * x);
    return 1.f - 2.f / (e + 1.f);
}

// ---------------- prep kernels ----------------
__global__ void k_gather_cast(const int* __restrict__ sent, const float* __restrict__ emb,
                              f16* __restrict__ xg) {
    int idx = blockIdx.x * 256 + threadIdx.x;      // 4096*512 exact
    int t = idx >> 9, e = idx & 511;
    xg[idx] = (f16)emb[(size_t)sent[t] * 512 + e];
}

__global__ void k_cast_f16(const float* __restrict__ src, f16* __restrict__ dst, unsigned n) {
    for (unsigned i = blockIdx.x * blockDim.x + threadIdx.x; i < n; i += gridDim.x * blockDim.x)
        dst[i] = (f16)src[i];
}

__global__ void k_prep_wrnn(const float* __restrict__ whh, int* __restrict__ wrnn) {
    int D = blockIdx.x * 256 + threadIdx.x;        // 65536 dwords exact
    int l = D & 63, c = (D >> 6) & 63, w = D >> 12;
    int k = c >> 4, q = c & 15, g = w & 7, hh = w >> 3;
    int o = hh * 256 + l * 4 + k;
    int res = 0;
    for (int b = 0; b < 4; ++b) {
        int j = g * 64 + q * 4 + b;
        float v = whh[o * 512 + j] * (127.0f / WMAX);
        int qv = __float2int_rn(v);
        qv = qv < -127 ? -127 : (qv > 127 ? 127 : qv);
        res |= (qv & 0xff) << (8 * b);
    }
    wrnn[D] = res;
}

// ---------------- K1: xp = x @ W_ih^T + b_ih + b_hh ----------------
// LDS tiles are XOR-swizzled: LDS[row][slot] holds global 16B-chunk slot^(row&7)
// (pre-swizzled global source since global_load_lds writes linearly — rule #21).
__launch_bounds__(256)
__global__ void k_gemm_xp(const f16* __restrict__ A, const f16* __restrict__ B,
                          const float* __restrict__ bih, const float* __restrict__ bhh,
                          float* __restrict__ xp) {
    __shared__ f16 As[128 * 64];
    __shared__ f16 Bs[128 * 64];
    int nb = blockIdx.x, mb = blockIdx.y;
    int tid = threadIdx.x;
    int lane = tid & 63, wv = tid >> 6;
    int wm = wv >> 1, wn = wv & 1;
    f32x4 acc[4][4] = {};
    for (int kk = 0; kk < 8; ++kk) {
        __syncthreads();
        for (int p = 0; p < 4; ++p) {
            int f = p * 256 + tid;
            int row = f >> 3;
            int c16 = (f & 7) ^ (row & 7);          // swizzled source chunk
            const f16* ga = A + ((size_t)(mb * 128 + row) * 512 + kk * 64 + c16 * 8);
            const f16* gb = B + ((size_t)(nb * 128 + row) * 512 + kk * 64 + c16 * 8);
            gload_lds16(ga, &As[(p * 256 + wv * 64) * 8]);
            gload_lds16(gb, &Bs[(p * 256 + wv * 64) * 8]);
        }
        __syncthreads();
        for (int k2 = 0; k2 < 2; ++k2) {
            int u = lane >> 4;
            f16x8 a[4], b[4];
            for (int mi = 0; mi < 4; ++mi) {
                int ra = wm * 64 + mi * 16 + (lane & 15);
                a[mi] = *(const f16x8*)&As[ra * 64 + ((k2 * 4 + u) ^ (ra & 7)) * 8];
            }
            for (int ni = 0; ni < 4; ++ni) {
                int rb = wn * 64 + ni * 16 + (lane & 15);
                b[ni] = *(const f16x8*)&Bs[rb * 64 + ((k2 * 4 + u) ^ (rb & 7)) * 8];
            }
            for (int mi = 0; mi < 4; ++mi)
                for (int ni = 0; ni < 4; ++ni)
                    acc[mi][ni] = __builtin_amdgcn_mfma_f32_16x16x32_f16(a[mi], b[ni], acc[mi][ni], 0, 0, 0);
        }
    }
    for (int mi = 0; mi < 4; ++mi)
        for (int ni = 0; ni < 4; ++ni)
            for (int r = 0; r < 4; ++r) {
                int row = mb * 128 + wm * 64 + mi * 16 + (lane >> 4) * 4 + r;
                int col = nb * 128 + wn * 64 + ni * 16 + (lane & 15);
                xp[(size_t)row * 512 + col] = acc[mi][ni][r] + bih[col] + bhh[col];
            }
}

// ---------------- K2: chunked RNN, int8 W in VGPRs ----------------
__launch_bounds__(1024)
__global__ void k_rnn(const int* __restrict__ wrnn, const float* __restrict__ xp,
                      f16* __restrict__ hs) {
    __shared__ __align__(16) int h8[128];
    __shared__ __align__(16) float part[8][512];
    const int tid = threadIdx.x;
    const int lane = tid & 63, wv = tid >> 6;
    const int g = wv & 7, hh = wv >> 3;
    const int chunk = blockIdx.x;                 // 0..255
    const int out_start = chunk * 16;
    const int t_start = out_start >= 128 ? out_start - 128 : 0;
    const int t_end = out_start + 16;

    int W[64];
#pragma unroll
    for (int cc = 0; cc < 64; ++cc) W[cc] = wrnn[(wv * 64 + cc) * 64 + lane];

    if (tid < 128) h8[tid] = 0;
    float4 xpv = {};
    if (tid < 128) xpv = *(const float4*)&xp[(size_t)t_start * 512 + tid * 4];
    __syncthreads();

    for (int t = t_start; t < t_end; ++t) {
        int hbuf[16];
#pragma unroll
        for (int q4 = 0; q4 < 4; ++q4)
            *(int4*)&hbuf[q4 * 4] = *(const int4*)&h8[g * 16 + q4 * 4];
        int a0 = 0, a1 = 0, a2 = 0, a3 = 0;
#pragma unroll
        for (int q = 0; q < 16; ++q) {
            int hq = hbuf[q];
            a0 = __builtin_amdgcn_sdot4(W[q], hq, a0, false);
            a1 = __builtin_amdgcn_sdot4(W[16 + q], hq, a1, false);
            a2 = __builtin_amdgcn_sdot4(W[32 + q], hq, a2, false);
            a3 = __builtin_amdgcn_sdot4(W[48 + q], hq, a3, false);
        }
        float4 pv;
        pv.x = (float)a0; pv.y = (float)a1; pv.z = (float)a2; pv.w = (float)a3;
        *(float4*)&part[g][hh * 256 + lane * 4] = pv;
        __syncthreads();
        if (tid < 128) {
            float sx = 0.f, sy = 0.f, sz = 0.f, sw = 0.f;
#pragma unroll
            for (int gg = 0; gg < 8; ++gg) {
                float4 p = *(const float4*)&part[gg][tid * 4];
                sx += p.x; sy += p.y; sz += p.z; sw += p.w;
            }
            const float DEQ = WMAX / (127.f * 127.f);
            float h0 = tanh_fast(sx * DEQ + xpv.x);
            float h1 = tanh_fast(sy * DEQ + xpv.y);
            float h2 = tanh_fast(sz * DEQ + xpv.z);
            float h3 = tanh_fast(sw * DEQ + xpv.w);
            if (t + 1 < t_end) xpv = *(const float4*)&xp[(size_t)(t + 1) * 512 + tid * 4];
            int q0 = __float2int_rn(h0 * 127.f), q1 = __float2int_rn(h1 * 127.f);
            int q2 = __float2int_rn(h2 * 127.f), q3 = __float2int_rn(h3 * 127.f);
            h8[tid] = (q0 & 255) | ((q1 & 255) << 8) | ((q2 & 255) << 16) | (q3 << 24);
            if (t >= out_start) {
                f16x4 hv;
                hv[0] = (f16)h0; hv[1] = (f16)h1; hv[2] = (f16)h2; hv[3] = (f16)h3;
                *(f16x4*)&hs[(size_t)t * 512 + tid * 4] = hv;
            }
        }
        __syncthreads();
    }
}

// ---------------- K3: logits GEMM + per-tile softmax partials ----------------
// MODE 0: store fp32 logits to d_out (fallback, k_sub later)
// MODE 1: store f16 logits to padded ws buffer (k_final later)
// grid: x = mb (32, inner -> B-tile shared across consecutive blocks),
//       y = nb (393). A (4MB) is LLC-resident; B read ~once from HBM.
template<int MODE>
__launch_bounds__(256)
__global__ void k_gemm_out(const f16* __restrict__ A, const f16* __restrict__ B,
                           const float* __restrict__ bout, float* __restrict__ out32,
                           f16* __restrict__ out16, float2* __restrict__ partials) {
    __shared__ f16 As[128 * 64];
    __shared__ f16 Bs[128 * 64];
    __shared__ float redm[2][128];
    __shared__ float reds[2][128];
    int mb = blockIdx.x, nb = blockIdx.y;
    int tid = threadIdx.x;
    int lane = tid & 63, wv = tid >> 6;
    int wm = wv >> 1, wn = wv & 1;
    f32x4 acc[4][4] = {};
    for (int kk = 0; kk < 8; ++kk) {
        __syncthreads();
        for (int p = 0; p < 4; ++p) {
            int f = p * 256 + tid;
            int row = f >> 3;
            int c16 = (f & 7) ^ (row & 7);          // swizzled source chunk
            const f16* ga = A + ((size_t)(mb * 128 + row) * 512 + kk * 64 + c16 * 8);
            int rg = nb * 128 + row; if (rg > N_TAGS - 1) rg = N_TAGS - 1;
            const f16* gb = B + ((size_t)rg * 512 + kk * 64 + c16 * 8);
            gload_lds16(ga, &As[(p * 256 + wv * 64) * 8]);
            gload_lds16(gb, &Bs[(p * 256 + wv * 64) * 8]);
        }
        __syncthreads();
        for (int k2 = 0; k2 < 2; ++k2) {
            int u = lane >> 4;
            f16x8 a[4], b[4];
            for (int mi = 0; mi < 4; ++mi) {
                int ra = wm * 64 + mi * 16 + (lane & 15);
                a[mi] = *(const f16x8*)&As[ra * 64 + ((k2 * 4 + u) ^ (ra & 7)) * 8];
            }
            for (int ni = 0; ni < 4; ++ni) {
                int rb = wn * 64 + ni * 16 + (lane & 15);
                b[ni] = *(const f16x8*)&Bs[rb * 64 + ((k2 * 4 + u) ^ (rb & 7)) * 8];
            }
            for (int mi = 0; mi < 4; ++mi)
                for (int ni = 0; ni < 4; ++ni)
                    acc[mi][ni] = __builtin_amdgcn_mfma_f32_16x16x32_f16(a[mi], b[ni], acc[mi][ni], 0, 0, 0);
        }
    }
    int colb[4]; float bo[4]; bool valid[4];
    for (int ni = 0; ni < 4; ++ni) {
        colb[ni] = nb * 128 + wn * 64 + ni * 16 + (lane & 15);
        valid[ni] = colb[ni] < N_TAGS;
        bo[ni] = valid[ni] ? bout[colb[ni]] : 0.f;
    }
    for (int mi = 0; mi < 4; ++mi)
        for (int r = 0; r < 4; ++r) {
            int lr = wm * 64 + mi * 16 + (lane >> 4) * 4 + r;
            int row = mb * 128 + lr;
            float v[4]; float mx = -3.4e38f;
            for (int ni = 0; ni < 4; ++ni) {
                v[ni] = acc[mi][ni][r] + bo[ni];
                if (valid[ni]) mx = fmaxf(mx, v[ni]);
            }
            for (int off = 1; off < 16; off <<= 1) mx = fmaxf(mx, __shfl_xor(mx, off));
            float se = 0.f;
            for (int ni = 0; ni < 4; ++ni) {
                if (valid[ni]) se += __expf(v[ni] - mx);
                if (MODE == 0) {
                    if (valid[ni]) out32[(size_t)row * N_TAGS + colb[ni]] = v[ni];
                } else {
                    out16[(size_t)row * LG_STRIDE + colb[ni]] = (f16)v[ni];  // pad cols ok
                }
            }
            for (int off = 1; off < 16; off <<= 1) se += __shfl_xor(se, off);
            if ((lane & 15) == 0) { redm[wn][lr] = mx; reds[wn][lr] = se; }
        }
    __syncthreads();
    if (tid < 128) {
        float m0 = redm[0][tid], m1 = redm[1][tid];
        float s0 = reds[0][tid], s1 = reds[1][tid];
        float m = fmaxf(m0, m1);
        float s = s0 * __expf(m0 - m) + s1 * __expf(m1 - m);
        partials[(size_t)nb * 4096 + mb * 128 + tid] = make_float2(m, s);
    }
}

// ---------------- K4: lse per row ----------------
__global__ void k_lse(const float2* __restrict__ partials, float* __restrict__ lse) {
    int wv = threadIdx.x >> 6, lane = threadIdx.x & 63;
    int row = blockIdx.x * 4 + wv;
    float m = -3.4e38f, s = 0.f;
    for (int p = lane; p < NBLK; p += 64) {
        float2 pr = partials[(size_t)p * 4096 + row];
        float nm = fmaxf(m, pr.x);
        s = s * __expf(m - nm) + pr.y * __expf(pr.x - nm);
        m = nm;
    }
    for (int off = 1; off < 64; off <<= 1) {
        float om = __shfl_xor(m, off), os = __shfl_xor(s, off);
        float nm = fmaxf(m, om);
        s = s * __expf(m - nm) + os * __expf(om - nm);
        m = nm;
    }
    if (lane == 0) lse[row] = m + logf(s);
}

// ---------------- K5a (fallback): out -= lse[row] ----------------
__global__ void k_sub(float* __restrict__ out, const float* __restrict__ lse, unsigned n) {
    unsigned stride = gridDim.x * blockDim.x;
    for (unsigned i = blockIdx.x * blockDim.x + threadIdx.x; i < n; i += stride) {
        unsigned row = i / (unsigned)N_TAGS;
        out[i] -= lse[row];
    }
}

// ---------------- K5b: out = (float)lg - lse[row], coalesced ----------------
__global__ void k_final(const f16* __restrict__ lg, const float* __restrict__ lse,
                        float* __restrict__ out) {
    int row = blockIdx.y;
    int base = blockIdx.x * 2048;
    float l = lse[row];
    const f16* lr = lg + (size_t)row * LG_STRIDE;
    float* orow = out + (size_t)row * N_TAGS;
#pragma unroll
    for (int j = 0; j < 8; ++j) {
        int cc = base + j * 256 + threadIdx.x;
        if (cc < N_TAGS) orow[cc] = (float)lr[cc] - l;
    }
}

extern "C" void kernel_launch(void* const* d_in, const int* in_sizes, int n_in,
                              void* d_out, int out_size, void* d_ws, size_t ws_size,
                              hipStream_t stream) {
    if (ws_size < WS_NEEDED) return;
    const int*   sent = (const int*)d_in[0];
    const float* emb  = (const float*)d_in[1];
    const float* wih  = (const float*)d_in[2];
    const float* whh  = (const float*)d_in[3];
    const float* bih  = (const float*)d_in[4];
    const float* bhh  = (const float*)d_in[5];
    const float* wout = (const float*)d_in[6];
    const float* bout = (const float*)d_in[7];
    char* ws = (char*)d_ws;
    f16*    xg    = (f16*)(ws + XG_OFF);
    f16*    wihf  = (f16*)(ws + WIH_OFF);
    int*    wrnn  = (int*)(ws + WRNN_OFF);
    float*  xp    = (float*)(ws + XP_OFF);
    f16*    hsb   = (f16*)(ws + HS_OFF);
    f16*    woutf = (f16*)(ws + WOUT_OFF);
    float2* part  = (float2*)(ws + PART_OFF);
    float*  lse   = (float*)(ws + LSE_OFF);
    f16*    lgp   = (f16*)(ws + LG_OFF);
    float*  out   = (float*)d_out;

    k_gather_cast<<<8192, 256, 0, stream>>>(sent, emb, xg);
    k_cast_f16<<<1024, 256, 0, stream>>>(wih, wihf, 512u * 512u);
    k_cast_f16<<<4096, 256, 0, stream>>>(wout, woutf, (unsigned)N_TAGS * 512u);
    k_prep_wrnn<<<256, 256, 0, stream>>>(whh, wrnn);
    k_gemm_xp<<<dim3(4, 32), 256, 0, stream>>>(xg, wihf, bih, bhh, xp);
    k_rnn<<<256, 1024, 0, stream>>>(wrnn, xp, hsb);
    if (ws_size >= WS_BIG) {
        k_gemm_out<1><<<dim3(32, NBLK), 256, 0, stream>>>(hsb, woutf, bout, nullptr, lgp, part);
        k_lse<<<1024, 256, 0, stream>>>(part, lse);
        k_final<<<dim3(25, 4096), 256, 0, stream>>>(lgp, lse, out);
    } else {
        k_gemm_out<0><<<dim3(32, NBLK), 256, 0, stream>>>(hsb, woutf, bout, out, nullptr, part);
        k_lse<<<1024, 256, 0, stream>>>(part, lse);
        k_sub<<<8192, 256, 0, stream>>>(out, lse, 4096u * (unsigned)N_TAGS);
    }
}

// Round 3
// 865.411 us; speedup vs baseline: 1.3830x; 1.2414x over previous
//
#include <hip/hip_runtime.h>

#define T_LEN 4096
#define H_DIM 512
#define N_TAGS 50257
#define LG_STRIDE 50304                 // N_TAGS padded to mult of 128 elems

typedef _Float16 f16;
typedef __attribute__((ext_vector_type(8))) _Float16 f16x8;
typedef __attribute__((ext_vector_type(4))) _Float16 f16x4;
typedef __attribute__((ext_vector_type(4))) float f32x4;

// ---------------- ws layout ----------------
#define XG_OFF    0ull                  // 4096*512 f16        = 4,194,304
#define WIH_OFF   4194304ull            // 512*512 f16         =   524,288
#define WRNN_OFF  4718592ull            // 65536 dwords        =   262,144
#define XP_OFF    5242880ull            // 4096*512 f32        = 8,388,608
#define HS_OFF    13631488ull           // 4096*512 f16        = 4,194,304
#define WOUT_OFF  17825792ull           // 50257*512 f16       = 51,463,168
#define PART_OFF  69288960ull           // 197*4096 float2     =  6,455,296
#define LSE_OFF   82166784ull           // 4096 f32            =    16,384
#define WS_NEEDED 82183168ull
#define LG_OFF    82183168ull           // 4096*50304 f16      = 412,090,368
#define WS_BIG    494273536ull

#define WMAX 0.04419417382f             // 1/sqrt(512)
#define NBLK2 197                       // ceil(50257/256)

__device__ __forceinline__ void gload_lds16(const void* g, void* l) {
    __builtin_amdgcn_global_load_lds(
        (const __attribute__((address_space(1))) unsigned*)g,
        (__attribute__((address_space(3))) unsigned*)l, 16, 0, 0);
}

__device__ __forceinline__ float tanh_fast(float x) {
    float e = __expf(2.f * x);
    return 1.f - 2.f / (e + 1.f);
}

// ---------------- prep kernels ----------------
__global__ void k_gather_cast(const int* __restrict__ sent, const float* __restrict__ emb,
                              f16* __restrict__ xg) {
    int idx = blockIdx.x * 256 + threadIdx.x;      // 4096*512 exact
    int t = idx >> 9, e = idx & 511;
    xg[idx] = (f16)emb[(size_t)sent[t] * 512 + e];
}

__global__ void k_cast_f16v(const float* __restrict__ src, f16* __restrict__ dst, unsigned n4) {
    for (unsigned i = blockIdx.x * blockDim.x + threadIdx.x; i < n4; i += gridDim.x * blockDim.x) {
        float4 v = *(const float4*)&src[i * 4];
        f16x4 h; h[0] = (f16)v.x; h[1] = (f16)v.y; h[2] = (f16)v.z; h[3] = (f16)v.w;
        *(f16x4*)&dst[i * 4] = h;
    }
}

__global__ void k_prep_wrnn(const float* __restrict__ whh, int* __restrict__ wrnn) {
    int D = blockIdx.x * 256 + threadIdx.x;        // 65536 dwords exact
    int l = D & 63, c = (D >> 6) & 63, w = D >> 12;
    int k = c >> 4, q = c & 15, g = w & 7, hh = w >> 3;
    int o = hh * 256 + l * 4 + k;
    int res = 0;
    for (int b = 0; b < 4; ++b) {
        int j = g * 64 + q * 4 + b;
        float v = whh[o * 512 + j] * (127.0f / WMAX);
        int qv = __float2int_rn(v);
        qv = qv < -127 ? -127 : (qv > 127 ? 127 : qv);
        res |= (qv & 0xff) << (8 * b);
    }
    wrnn[D] = res;
}

// ---------------- K1: xp = x @ W_ih^T + b_ih + b_hh (128^2, unchanged) ----------------
__launch_bounds__(256)
__global__ void k_gemm_xp(const f16* __restrict__ A, const f16* __restrict__ B,
                          const float* __restrict__ bih, const float* __restrict__ bhh,
                          float* __restrict__ xp) {
    __shared__ f16 As[128 * 64];
    __shared__ f16 Bs[128 * 64];
    int nb = blockIdx.x, mb = blockIdx.y;
    int tid = threadIdx.x;
    int lane = tid & 63, wv = tid >> 6;
    int wm = wv >> 1, wn = wv & 1;
    f32x4 acc[4][4] = {};
    for (int kk = 0; kk < 8; ++kk) {
        __syncthreads();
        for (int p = 0; p < 4; ++p) {
            int f = p * 256 + tid;
            int row = f >> 3;
            int c16 = (f & 7) ^ (row & 7);
            const f16* ga = A + ((size_t)(mb * 128 + row) * 512 + kk * 64 + c16 * 8);
            const f16* gb = B + ((size_t)(nb * 128 + row) * 512 + kk * 64 + c16 * 8);
            gload_lds16(ga, &As[(p * 256 + wv * 64) * 8]);
            gload_lds16(gb, &Bs[(p * 256 + wv * 64) * 8]);
        }
        __syncthreads();
        for (int k2 = 0; k2 < 2; ++k2) {
            int u = lane >> 4;
            f16x8 a[4], b[4];
            for (int mi = 0; mi < 4; ++mi) {
                int ra = wm * 64 + mi * 16 + (lane & 15);
                a[mi] = *(const f16x8*)&As[ra * 64 + ((k2 * 4 + u) ^ (ra & 7)) * 8];
            }
            for (int ni = 0; ni < 4; ++ni) {
                int rb = wn * 64 + ni * 16 + (lane & 15);
                b[ni] = *(const f16x8*)&Bs[rb * 64 + ((k2 * 4 + u) ^ (rb & 7)) * 8];
            }
            for (int mi = 0; mi < 4; ++mi)
                for (int ni = 0; ni < 4; ++ni)
                    acc[mi][ni] = __builtin_amdgcn_mfma_f32_16x16x32_f16(a[mi], b[ni], acc[mi][ni], 0, 0, 0);
        }
    }
    for (int mi = 0; mi < 4; ++mi)
        for (int ni = 0; ni < 4; ++ni)
            for (int r = 0; r < 4; ++r) {
                int row = mb * 128 + wm * 64 + mi * 16 + (lane >> 4) * 4 + r;
                int col = nb * 128 + wn * 64 + ni * 16 + (lane & 15);
                xp[(size_t)row * 512 + col] = acc[mi][ni][r] + bih[col] + bhh[col];
            }
}

// ---------------- K2: chunked RNN, int8 W in VGPRs (warm-up 64) ----------------
__launch_bounds__(1024)
__global__ void k_rnn(const int* __restrict__ wrnn, const float* __restrict__ xp,
                      f16* __restrict__ hs) {
    __shared__ __align__(16) int h8[128];
    __shared__ __align__(16) float part[8][512];
    const int tid = threadIdx.x;
    const int lane = tid & 63, wv = tid >> 6;
    const int g = wv & 7, hh = wv >> 3;
    const int chunk = blockIdx.x;                 // 0..255
    const int out_start = chunk * 16;
    const int t_start = out_start >= 64 ? out_start - 64 : 0;
    const int t_end = out_start + 16;

    int W[64];
#pragma unroll
    for (int cc = 0; cc < 64; ++cc) W[cc] = wrnn[(wv * 64 + cc) * 64 + lane];

    if (tid < 128) h8[tid] = 0;
    float4 xpv = {};
    if (tid < 128) xpv = *(const float4*)&xp[(size_t)t_start * 512 + tid * 4];
    __syncthreads();

    for (int t = t_start; t < t_end; ++t) {
        int hbuf[16];
#pragma unroll
        for (int q4 = 0; q4 < 4; ++q4)
            *(int4*)&hbuf[q4 * 4] = *(const int4*)&h8[g * 16 + q4 * 4];
        int a0 = 0, a1 = 0, a2 = 0, a3 = 0;
#pragma unroll
        for (int q = 0; q < 16; ++q) {
            int hq = hbuf[q];
            a0 = __builtin_amdgcn_sdot4(W[q], hq, a0, false);
            a1 = __builtin_amdgcn_sdot4(W[16 + q], hq, a1, false);
            a2 = __builtin_amdgcn_sdot4(W[32 + q], hq, a2, false);
            a3 = __builtin_amdgcn_sdot4(W[48 + q], hq, a3, false);
        }
        float4 pv;
        pv.x = (float)a0; pv.y = (float)a1; pv.z = (float)a2; pv.w = (float)a3;
        *(float4*)&part[g][hh * 256 + lane * 4] = pv;
        __syncthreads();
        if (tid < 128) {
            float sx = 0.f, sy = 0.f, sz = 0.f, sw = 0.f;
#pragma unroll
            for (int gg = 0; gg < 8; ++gg) {
                float4 p = *(const float4*)&part[gg][tid * 4];
                sx += p.x; sy += p.y; sz += p.z; sw += p.w;
            }
            const float DEQ = WMAX / (127.f * 127.f);
            float h0 = tanh_fast(sx * DEQ + xpv.x);
            float h1 = tanh_fast(sy * DEQ + xpv.y);
            float h2 = tanh_fast(sz * DEQ + xpv.z);
            float h3 = tanh_fast(sw * DEQ + xpv.w);
            if (t + 1 < t_end) xpv = *(const float4*)&xp[(size_t)(t + 1) * 512 + tid * 4];
            int q0 = __float2int_rn(h0 * 127.f), q1 = __float2int_rn(h1 * 127.f);
            int q2 = __float2int_rn(h2 * 127.f), q3 = __float2int_rn(h3 * 127.f);
            h8[tid] = (q0 & 255) | ((q1 & 255) << 8) | ((q2 & 255) << 16) | (q3 << 24);
            if (t >= out_start) {
                f16x4 hv;
                hv[0] = (f16)h0; hv[1] = (f16)h1; hv[2] = (f16)h2; hv[3] = (f16)h3;
                *(f16x4*)&hs[(size_t)t * 512 + tid * 4] = hv;
            }
        }
        __syncthreads();
    }
}

// ---------------- K3: 256x256 2-phase double-buffered GEMM + softmax partials ----------
// 512 threads = 8 waves (2M x 4N); wave tile 128x64; BK=64, K=512 -> 8 steps.
// LDS 128KB: A0,B0,A1,B1 each 32KB. XOR swizzle chunk^=(row&7) both sides.
// MFMA operands SWAPPED: acc = mfma(bfrag, afrag, acc) -> lane holds 4 consecutive
// output COLS per (mi,ni): col = cbase[ni]+r, row = mi*16+(lane&15).
template<int MODE>
__launch_bounds__(512)
__global__ void k_gemm_out(const f16* __restrict__ A, const f16* __restrict__ B,
                           const float* __restrict__ bout, float* __restrict__ out32,
                           f16* __restrict__ lg, float2* __restrict__ partials) {
    __shared__ __align__(16) char smem[131072];
    float* pmS = (float*)smem;            // [4][256] overlay on A0 (dead at epilogue)
    float* psS = (float*)(smem + 4096);   // [4][256]

    const int tid = threadIdx.x;
    const int lane = tid & 63, wv = tid >> 6;
    const int wm = wv >> 2, wn = wv & 3;          // 2 x 4 waves
    const int l15 = lane & 15, u = lane >> 4;

    int bid = blockIdx.x;                          // 3152 = 8 * 394
    int swz = (bid & 7) * 394 + (bid >> 3);        // XCD-contiguous
    int mb = swz & 15;                             // fast: share B tile in-XCD
    int nb = swz >> 4;                             // 0..196

    // staging source offsets (4 rounds each for A and B)
    const int srow = tid >> 3;                     // 0..63
    const int sc   = (tid & 7) ^ (srow & 7);       // swizzled chunk
    size_t aoff[4], boff[4];
#pragma unroll
    for (int p = 0; p < 4; ++p) {
        int ra = mb * 256 + p * 64 + srow;
        aoff[p] = (size_t)ra * 512 + sc * 8;
        int rb = nb * 256 + p * 64 + srow;
        if (rb > N_TAGS - 1) rb = N_TAGS - 1;
        boff[p] = (size_t)rb * 512 + sc * 8;
    }
    const int ldst = wv * 512;                     // wave-uniform f16 offset within round

    f32x4 acc[8][4] = {};

#define STAGE(KT, BUF) do {                                                    \
    f16* Ad = (f16*)(smem + (BUF) * 65536);                                    \
    f16* Bd = Ad + 16384;                                                      \
    _Pragma("unroll")                                                          \
    for (int p = 0; p < 4; ++p)                                                \
        gload_lds16(A + aoff[p] + (size_t)(KT) * 64, Ad + p * 4096 + ldst);    \
    _Pragma("unroll")                                                          \
    for (int p = 0; p < 4; ++p)                                                \
        gload_lds16(B + boff[p] + (size_t)(KT) * 64, Bd + p * 4096 + ldst);    \
} while (0)

    STAGE(0, 0);
    __syncthreads();                               // drains vmcnt

    int cur = 0;
    for (int t = 0; t < 8; ++t) {
        if (t < 7) STAGE(t + 1, cur ^ 1);
        const f16* Ab = (const f16*)(smem + cur * 65536);
        const f16* Bb = Ab + 16384;
#pragma unroll
        for (int k2 = 0; k2 < 2; ++k2) {
            f16x8 bfr[4];
#pragma unroll
            for (int ni = 0; ni < 4; ++ni) {
                int rb = wn * 64 + ni * 16 + l15;
                bfr[ni] = *(const f16x8*)&Bb[rb * 64 + ((k2 * 4 + u) ^ (lane & 7)) * 8];
            }
#pragma unroll
            for (int mi = 0; mi < 8; ++mi) {
                int ra = wm * 128 + mi * 16 + l15;
                f16x8 af = *(const f16x8*)&Ab[ra * 64 + ((k2 * 4 + u) ^ (lane & 7)) * 8];
#pragma unroll
                for (int ni = 0; ni < 4; ++ni)
                    acc[mi][ni] = __builtin_amdgcn_mfma_f32_16x16x32_f16(bfr[ni], af, acc[mi][ni], 0, 0, 0);
            }
        }
        if (t < 7) __syncthreads();                // vmcnt drain + buffer handoff
        cur ^= 1;
    }

    // ---- epilogue: swapped layout -> 4 consecutive cols per lane ----
    const float NEG = -3.4e38f;
    int cbase[4]; float bo[4][4];
#pragma unroll
    for (int ni = 0; ni < 4; ++ni) {
        cbase[ni] = nb * 256 + wn * 64 + ni * 16 + u * 4;
#pragma unroll
        for (int r = 0; r < 4; ++r) {
            int c = cbase[ni] + r;
            bo[ni][r] = (c < N_TAGS) ? bout[c] : 0.f;
        }
    }
#pragma unroll
    for (int mi = 0; mi < 8; ++mi) {
        float vv[4][4]; float mx = NEG;
#pragma unroll
        for (int ni = 0; ni < 4; ++ni)
#pragma unroll
            for (int r = 0; r < 4; ++r) {
                int c = cbase[ni] + r;
                float v = acc[mi][ni][r] + bo[ni][r];
                v = (c < N_TAGS) ? v : NEG;
                vv[ni][r] = v;
                mx = fmaxf(mx, v);
            }
        mx = fmaxf(mx, __shfl_xor(mx, 16));
        mx = fmaxf(mx, __shfl_xor(mx, 32));
        float se = 0.f;
#pragma unroll
        for (int ni = 0; ni < 4; ++ni)
#pragma unroll
            for (int r = 0; r < 4; ++r)
                se += __expf(vv[ni][r] - mx);
        se += __shfl_xor(se, 16);
        se += __shfl_xor(se, 32);
        int row_g = mb * 256 + wm * 128 + mi * 16 + l15;
        if (MODE == 1) {
#pragma unroll
            for (int ni = 0; ni < 4; ++ni) {
                if (cbase[ni] < LG_STRIDE) {
                    f16x4 h;
                    h[0] = (f16)vv[ni][0]; h[1] = (f16)vv[ni][1];
                    h[2] = (f16)vv[ni][2]; h[3] = (f16)vv[ni][3];
                    *(f16x4*)&lg[(size_t)row_g * LG_STRIDE + cbase[ni]] = h;
                }
            }
        } else {
#pragma unroll
            for (int ni = 0; ni < 4; ++ni)
#pragma unroll
                for (int r = 0; r < 4; ++r) {
                    int c = cbase[ni] + r;
                    if (c < N_TAGS) out32[(size_t)row_g * N_TAGS + c] = vv[ni][r];
                }
        }
        if (u == 0) {
            int idx = wm * 128 + mi * 16 + l15;
            pmS[wn * 256 + idx] = mx;
            psS[wn * 256 + idx] = se;
        }
    }
    __syncthreads();
    if (tid < 256) {
        float m = pmS[tid];
        m = fmaxf(m, pmS[256 + tid]);
        m = fmaxf(m, pmS[512 + tid]);
        m = fmaxf(m, pmS[768 + tid]);
        float s = 0.f;
#pragma unroll
        for (int w2 = 0; w2 < 4; ++w2)
            s += psS[w2 * 256 + tid] * __expf(pmS[w2 * 256 + tid] - m);
        partials[(size_t)nb * 4096 + mb * 256 + tid] = make_float2(m, s);
    }
#undef STAGE
}

// ---------------- K4: lse per row ----------------
__global__ void k_lse(const float2* __restrict__ partials, float* __restrict__ lse) {
    int wv = threadIdx.x >> 6, lane = threadIdx.x & 63;
    int row = blockIdx.x * 4 + wv;
    float m = -3.4e38f, s = 0.f;
    for (int p = lane; p < NBLK2; p += 64) {
        float2 pr = partials[(size_t)p * 4096 + row];
        float nm = fmaxf(m, pr.x);
        s = s * __expf(m - nm) + pr.y * __expf(pr.x - nm);
        m = nm;
    }
    for (int off = 1; off < 64; off <<= 1) {
        float om = __shfl_xor(m, off), os = __shfl_xor(s, off);
        float nm = fmaxf(m, om);
        s = s * __expf(m - nm) + os * __expf(om - nm);
        m = nm;
    }
    if (lane == 0) lse[row] = m + logf(s);
}

// ---------------- K5a (fallback): out -= lse[row] ----------------
__global__ void k_sub(float* __restrict__ out, const float* __restrict__ lse, unsigned n) {
    unsigned stride = gridDim.x * blockDim.x;
    for (unsigned i = blockIdx.x * blockDim.x + threadIdx.x; i < n; i += stride) {
        unsigned row = i / (unsigned)N_TAGS;
        out[i] -= lse[row];
    }
}

// ---------------- K5b: out = (float)lg - lse[row], coalesced ----------------
__global__ void k_final(const f16* __restrict__ lg, const float* __restrict__ lse,
                        float* __restrict__ out) {
    int row = blockIdx.y;
    int base = blockIdx.x * 2048;
    float l = lse[row];
    const f16* lr = lg + (size_t)row * LG_STRIDE;
    float* orow = out + (size_t)row * N_TAGS;
#pragma unroll
    for (int j = 0; j < 8; ++j) {
        int cc = base + j * 256 + threadIdx.x;
        if (cc < N_TAGS) orow[cc] = (float)lr[cc] - l;
    }
}

extern "C" void kernel_launch(void* const* d_in, const int* in_sizes, int n_in,
                              void* d_out, int out_size, void* d_ws, size_t ws_size,
                              hipStream_t stream) {
    if (ws_size < WS_NEEDED) return;
    const int*   sent = (const int*)d_in[0];
    const float* emb  = (const float*)d_in[1];
    const float* wih  = (const float*)d_in[2];
    const float* whh  = (const float*)d_in[3];
    const float* bih  = (const float*)d_in[4];
    const float* bhh  = (const float*)d_in[5];
    const float* wout = (const float*)d_in[6];
    const float* bout = (const float*)d_in[7];
    char* ws = (char*)d_ws;
    f16*    xg    = (f16*)(ws + XG_OFF);
    f16*    wihf  = (f16*)(ws + WIH_OFF);
    int*    wrnn  = (int*)(ws + WRNN_OFF);
    float*  xp    = (float*)(ws + XP_OFF);
    f16*    hsb   = (f16*)(ws + HS_OFF);
    f16*    woutf = (f16*)(ws + WOUT_OFF);
    float2* part  = (float2*)(ws + PART_OFF);
    float*  lse   = (float*)(ws + LSE_OFF);
    f16*    lgp   = (f16*)(ws + LG_OFF);
    float*  out   = (float*)d_out;

    k_gather_cast<<<8192, 256, 0, stream>>>(sent, emb, xg);
    k_cast_f16v<<<256, 256, 0, stream>>>(wih, wihf, 512u * 512u / 4u);
    k_cast_f16v<<<2048, 256, 0, stream>>>(wout, woutf, (unsigned)N_TAGS * 512u / 4u);
    k_prep_wrnn<<<256, 256, 0, stream>>>(whh, wrnn);
    k_gemm_xp<<<dim3(4, 32), 256, 0, stream>>>(xg, wihf, bih, bhh, xp);
    k_rnn<<<256, 1024, 0, stream>>>(wrnn, xp, hsb);
    if (ws_size >= WS_BIG) {
        k_gemm_out<1><<<3152, 512, 0, stream>>>(hsb, woutf, bout, nullptr, lgp, part);
        k_lse<<<1024, 256, 0, stream>>>(part, lse);
        k_final<<<dim3(25, 4096), 256, 0, stream>>>(lgp, lse, out);
    } else {
        k_gemm_out<0><<<3152, 512, 0, stream>>>(hsb, woutf, bout, out, nullptr, part);
        k_lse<<<1024, 256, 0, stream>>>(part, lse);
        k_sub<<<8192, 256, 0, stream>>>(out, lse, 4096u * (unsigned)N_TAGS);
    }
}